// Round 21
// baseline (319.179 us; speedup 1.0000x reference)
//
#include <hip/hip_runtime.h>
#include <stdint.h>

#define NUM_HEADS 12
#define HEAD_DIM  64
#define HWDIM     56
#define PHDIM     28
#define NTOK      785     // 28*28+1
#define NIN       3137    // 56*56+1
#define BATCH     16
#define DMODEL    768
#define BHCNT     192     // BATCH*NUM_HEADS
#define LOG2E     1.44269504f

typedef __attribute__((ext_vector_type(8))) short bf16x8;
typedef __attribute__((ext_vector_type(4))) short s16x4;
typedef __attribute__((ext_vector_type(4))) float f32x4;

static __device__ __forceinline__ float bf2f(short s) {
  unsigned u = ((unsigned)(unsigned short)s) << 16;
  float f; __builtin_memcpy(&f, &u, 4); return f;
}
static __device__ __forceinline__ short f2bf(float f) {
  unsigned u; __builtin_memcpy(&u, &f, 4);
  unsigned r = u + 0x7FFFu + ((u >> 16) & 1u);
  return (short)(r >> 16);
}
static __device__ __forceinline__ float fexp2(float x) {
#if defined(__has_builtin)
#if __has_builtin(__builtin_amdgcn_exp2f)
  return __builtin_amdgcn_exp2f(x);
#else
  return exp2f(x);
#endif
#else
  return exp2f(x);
#endif
}

// bijective XCD chunking (m204)
static __device__ __forceinline__ int xcd_chunk(int orig, int nwg) {
  int xcd = orig & 7;
  int within = orig >> 3;
  int q = nwg >> 3, r = nwg & 7;
  int base = (xcd < r) ? xcd * (q + 1) : r * (q + 1) + (xcd - r) * q;
  return base + within;
}

#if defined(__has_builtin)
#if __has_builtin(__builtin_amdgcn_global_load_lds)
#define HAVE_GLLDS 1
#endif
#endif

static __device__ __forceinline__ void gl_lds16(const short* g, short* l) {
#ifdef HAVE_GLLDS
  __builtin_amdgcn_global_load_lds(
      (const __attribute__((address_space(1))) void*)g,
      (__attribute__((address_space(3))) void*)l, 16, 0, 0);
#else
  int lane = threadIdx.x & 63;
  *(bf16x8*)(l + lane * 8) = *(const bf16x8*)g;
#endif
}

// ---------------------------------------------------------------- pool + LN
__global__ __launch_bounds__(192) void pool_ln_kernel(
    const float* __restrict__ x,
    const float* __restrict__ wq9, const float* __restrict__ wk9, const float* __restrict__ wv9,
    const float* __restrict__ gq, const float* __restrict__ bq,
    const float* __restrict__ gk, const float* __restrict__ bk,
    const float* __restrict__ gv, const float* __restrict__ bv,
    short* __restrict__ Pq, short* __restrict__ Pk, short* __restrict__ Pv)
{
  __shared__ __align__(16) float wt_s[3][9][64];   // [conv][tap][c]
  int tid = threadIdx.x;
  int blk = xcd_chunk(blockIdx.x, 16 * 197);   // L2 locality: neighbors same XCD
  int b = blk / 197;
  int n0 = (blk - b * 197) * 4;

  for (int idx = tid; idx < 3 * 576; idx += 192) {
    int conv = idx / 576, rem = idx - conv * 576;
    int c = rem / 9, tap = rem - c * 9;
    const float* wsrc = (conv == 0) ? wq9 : (conv == 1) ? wk9 : wv9;
    wt_s[conv][tap][c] = wsrc[c * 9 + tap];
  }
  __syncthreads();

  int ch0 = tid * 4;
  int c4 = ch0 & 63;
  f32x4 g_q = *(const f32x4*)&gq[c4], b_q = *(const f32x4*)&bq[c4];
  f32x4 g_k = *(const f32x4*)&gk[c4], b_k = *(const f32x4*)&bk[c4];
  f32x4 g_v = *(const f32x4*)&gv[c4], b_v = *(const f32x4*)&bv[c4];

  for (int tt = 0; tt < 4; ++tt) {
    int n = n0 + tt;
    if (n >= NTOK) break;
    f32x4 aq = (f32x4){0.f, 0.f, 0.f, 0.f}, ak = aq, av = aq;
    if (n == 0) {
      f32x4 x4 = *(const f32x4*)&x[((size_t)b * NIN) * DMODEL + ch0];
      aq = ak = av = x4;
    } else {
      int s = n - 1;
      int i = s / PHDIM, j = s - i * PHDIM;
#pragma unroll
      for (int di = 0; di < 3; ++di) {
        int ii = 2 * i - 1 + di;
        if (ii < 0 || ii >= HWDIM) continue;
#pragma unroll
        for (int dj = 0; dj < 3; ++dj) {
          int jj = 2 * j - 1 + dj;
          if (jj < 0 || jj >= HWDIM) continue;
          f32x4 x4 = *(const f32x4*)&x[((size_t)b * NIN + 1 + ii * HWDIM + jj) * DMODEL + ch0];
          int tap = di * 3 + dj;
          f32x4 w0 = *(const f32x4*)&wt_s[0][tap][c4];
          f32x4 w1 = *(const f32x4*)&wt_s[1][tap][c4];
          f32x4 w2 = *(const f32x4*)&wt_s[2][tap][c4];
          aq += w0 * x4; ak += w1 * x4; av += w2 * x4;
        }
      }
    }
    size_t obase = ((size_t)b * NTOK + n) * DMODEL + ch0;
    {
      float sm = aq[0] + aq[1] + aq[2] + aq[3];
#pragma unroll
      for (int m = 1; m < 16; m <<= 1) sm += __shfl_xor(sm, m);
      float mn = sm * (1.f / 64.f);
      f32x4 d = aq - mn;
      float vs = d[0]*d[0] + d[1]*d[1] + d[2]*d[2] + d[3]*d[3];
#pragma unroll
      for (int m = 1; m < 16; m <<= 1) vs += __shfl_xor(vs, m);
      float rs = rsqrtf(vs * (1.f / 64.f) + 1e-5f);
      s16x4 o;
#pragma unroll
      for (int e = 0; e < 4; ++e) o[e] = f2bf(d[e] * rs * g_q[e] + b_q[e]);
      *(s16x4*)&Pq[obase] = o;
    }
    {
      float sm = ak[0] + ak[1] + ak[2] + ak[3];
#pragma unroll
      for (int m = 1; m < 16; m <<= 1) sm += __shfl_xor(sm, m);
      float mn = sm * (1.f / 64.f);
      f32x4 d = ak - mn;
      float vs = d[0]*d[0] + d[1]*d[1] + d[2]*d[2] + d[3]*d[3];
#pragma unroll
      for (int m = 1; m < 16; m <<= 1) vs += __shfl_xor(vs, m);
      float rs = rsqrtf(vs * (1.f / 64.f) + 1e-5f);
      s16x4 o;
#pragma unroll
      for (int e = 0; e < 4; ++e) o[e] = f2bf(d[e] * rs * g_k[e] + b_k[e]);
      *(s16x4*)&Pk[obase] = o;
    }
    {
      float sm = av[0] + av[1] + av[2] + av[3];
#pragma unroll
      for (int m = 1; m < 16; m <<= 1) sm += __shfl_xor(sm, m);
      float mn = sm * (1.f / 64.f);
      f32x4 d = av - mn;
      float vs = d[0]*d[0] + d[1]*d[1] + d[2]*d[2] + d[3]*d[3];
#pragma unroll
      for (int m = 1; m < 16; m <<= 1) vs += __shfl_xor(vs, m);
      float rs = rsqrtf(vs * (1.f / 64.f) + 1e-5f);
      s16x4 o;
#pragma unroll
      for (int e = 0; e < 4; ++e) o[e] = f2bf(d[e] * rs * g_v[e] + b_v[e]);
      *(s16x4*)&Pv[obase] = o;
    }
  }
}

// ------------------------------------------------- weight transpose fp32->bf16
__global__ __launch_bounds__(256) void trans_kernel(
    const float* __restrict__ s0, const float* __restrict__ s1,
    const float* __restrict__ s2, const float* __restrict__ s3,
    short* __restrict__ d0, short* __restrict__ d1,
    short* __restrict__ d2, short* __restrict__ d3)
{
  __shared__ float tile[32][33];
  int z = blockIdx.z;
  const float* s = (z == 0) ? s0 : (z == 1) ? s1 : (z == 2) ? s2 : s3;
  short* d = (z == 0) ? d0 : (z == 1) ? d1 : (z == 2) ? d2 : d3;
  int k0 = blockIdx.x * 32, n0 = blockIdx.y * 32;
  int tx = threadIdx.x, ty = threadIdx.y;   // 32 x 8
#pragma unroll
  for (int jj = 0; jj < 4; ++jj)
    tile[ty + jj * 8][tx] = s[(size_t)(k0 + ty + jj * 8) * DMODEL + n0 + tx];
  __syncthreads();
#pragma unroll
  for (int jj = 0; jj < 4; ++jj)
    d[(size_t)(n0 + ty + jj * 8) * DMODEL + k0 + tx] = f2bf(tile[tx][ty + jj * 8]);
}

// ------------------------------------------------------------- GEMM core (R15)
// 128x64 tile, BK=32, 2-phase dbuf, 4 waves each owning 64x32.
static __device__ __forceinline__ void gemm_core(
    short* As, short* Bs,
    const short* __restrict__ A, const short* __restrict__ Bt,
    const float* __restrict__ bias, void* __restrict__ outp, void* __restrict__ outp2,
    int rowbase, int colbase, int M, int Nn, int mode)
{
  const int K = DMODEL;
  int tid = threadIdx.x;
  int wid = tid >> 6, lane = tid & 63;
  int lg = lane >> 4, lq = lane & 15;
  int wm = wid >> 1, wn = wid & 1;

  f32x4 acc[4][2];
#pragma unroll
  for (int i = 0; i < 4; ++i)
#pragma unroll
    for (int j = 0; j < 2; ++j) acc[i][j] = (f32x4){0.f, 0.f, 0.f, 0.f};

  const short* AgP[2];
  const short* BgP;
  {
#pragma unroll
    for (int m = 0; m < 2; ++m) {
      int ch = m * 256 + tid;
      int row = ch >> 2, j = ch & 3;
      int gcol = (j ^ (row & 3)) << 3;
      int ar = min(rowbase + row, M - 1);
      AgP[m] = A + (size_t)ar * K + gcol;
    }
    int ch = tid;
    int row = ch >> 2, j = ch & 3;
    int gcol = (j ^ (row & 3)) << 3;
    int br = min(colbase + row, Nn - 1);
    BgP = Bt + (size_t)br * K + gcol;
  }

  auto stage = [&](int kt, int buf) __attribute__((always_inline)) {
    short* Ab = As + buf * 4096;
    short* Bb = Bs + buf * 2048;
#pragma unroll
    for (int m = 0; m < 2; ++m)
      gl_lds16(AgP[m] + kt, Ab + m * 2048 + wid * 512);
    gl_lds16(BgP + kt, Bb + wid * 512);
  };

  stage(0, 0);
  __syncthreads();
  int cur = 0;
  for (int kt = 0; kt < K; kt += 32) {
    if (kt + 32 < K) stage(kt + 32, cur ^ 1);
    const short* Ac = As + cur * 4096;
    const short* Bc = Bs + cur * 2048;
    bf16x8 aFrag[4], bFrag[2];
#pragma unroll
    for (int mi = 0; mi < 4; ++mi) {
      int r = wm * 64 + mi * 16 + lq;
      int slot = lg ^ (r & 3);
      aFrag[mi] = *(const bf16x8*)&Ac[r * 32 + slot * 8];
    }
#pragma unroll
    for (int ni = 0; ni < 2; ++ni) {
      int r = wn * 32 + ni * 16 + lq;
      int slot = lg ^ (r & 3);
      bFrag[ni] = *(const bf16x8*)&Bc[r * 32 + slot * 8];
    }
    __builtin_amdgcn_s_setprio(1);
#pragma unroll
    for (int mi = 0; mi < 4; ++mi)
#pragma unroll
      for (int ni = 0; ni < 2; ++ni)
        acc[mi][ni] = __builtin_amdgcn_mfma_f32_16x16x32_bf16(aFrag[mi], bFrag[ni], acc[mi][ni], 0, 0, 0);
    __builtin_amdgcn_s_setprio(0);
    __syncthreads();
    cur ^= 1;
  }

  if (mode >= 3) {
    int myhead = colbase >> 6;
#pragma unroll
    for (int mi = 0; mi < 4; ++mi) {
      int rowq = rowbase + wm * 64 + mi * 16 + lg * 4;
#pragma unroll
      for (int r = 0; r < 4; ++r) {
        int row = rowq + r;
        if (row < M) {
          int bb = row / NTOK, nn = row - bb * NTOK;
          size_t abase = ((size_t)(bb * NUM_HEADS + myhead) * NTOK + nn) * 128;
#pragma unroll
          for (int ni = 0; ni < 2; ++ni) {
            int col = colbase + wn * 32 + ni * 16 + lq;
            int c = col & 63;
            float v = acc[mi][ni][r] + bias[col];
            ((short*)outp2)[abase + c] = f2bf(v);
          }
        }
      }
    }
    // aug upper half: every block writes its own head (no stale-memory deps)
    {
      int rz = rowbase + wn * 64 + wm * 32 + (lane >> 1);   // 1 writer per row
      if ((lane & 1) == 0 && rz < M) {
        int bb = rz / NTOK, nn = rz - bb * NTOK;
        short* dst = (short*)outp2 + ((size_t)(bb * NUM_HEADS + myhead) * NTOK + nn) * 128 + 64;
        bf16x8 z = {0, 0, 0, 0, 0, 0, 0, 0};
        if (mode == 3) {
          // relbias overwrites dims [64:120) for nn>=1; we own [120:128)
          *(bf16x8*)(dst + 56) = z;
          if (nn == 0) {
#pragma unroll
            for (int zc = 0; zc < 7; ++zc) *(bf16x8*)(dst + zc * 8) = z;
          }
        } else {
          int ki = -100, kj = -100;
          if (nn >= 1) { int km1 = nn - 1; ki = km1 / PHDIM; kj = km1 - ki * PHDIM; }
#pragma unroll
          for (int zc = 0; zc < 8; ++zc) {
            bf16x8 o = {0, 0, 0, 0, 0, 0, 0, 0};
#pragma unroll
            for (int e = 0; e < 8; ++e) {
              int d = 64 + zc * 8 + e;
              if (d == 64 + ki || d == 92 + kj) o[e] = (short)0x3F80;
            }
            *(bf16x8*)(dst + zc * 8) = o;
          }
        }
      }
    }
    return;
  }

#pragma unroll
  for (int mi = 0; mi < 4; ++mi) {
    int rowq = rowbase + wm * 64 + mi * 16 + lg * 4;
#pragma unroll
    for (int r = 0; r < 4; ++r) {
      int row = rowq + r;
      if (row < M) {
        if (mode == 2) {
          float bb = bias[row];
#pragma unroll
          for (int ni = 0; ni < 2; ++ni) {
            int col = colbase + wn * 32 + ni * 16 + lq;
            if (col < Nn) {
              int b = col / NTOK, n = col - b * NTOK;
              float v = acc[mi][ni][r] + bb;
              ((short*)outp)[((size_t)b * DMODEL + row) * NTOK + n] = f2bf(v);
            }
          }
        } else {
#pragma unroll
          for (int ni = 0; ni < 2; ++ni) {
            int col = colbase + wn * 32 + ni * 16 + lq;
            float v = acc[mi][ni][r] + bias[col];
            ((float*)outp)[(size_t)row * DMODEL + col] = v;
          }
        }
      }
    }
  }
}

__global__ __launch_bounds__(256, 6) void gemm_qkv_kernel(
    const short* __restrict__ Pq, const short* __restrict__ WqT,
    const float* __restrict__ bq, short* __restrict__ qaug,
    const short* __restrict__ Pk, const short* __restrict__ WkT,
    const float* __restrict__ bk, short* __restrict__ kaug,
    const short* __restrict__ WvT, const short* __restrict__ Pv,
    const float* __restrict__ bv, short* __restrict__ vtg)
{
  __shared__ short As[2 * 4096];
  __shared__ short Bs[2 * 2048];
  const int NWG = 3558;
  int lid = xcd_chunk(blockIdx.x, NWG);
  if (lid < 2376) {
    int which = lid / 1188;
    int sub = lid - which * 1188;
    int rowbase = (sub / 12) * 128;
    int colbase = (sub % 12) * 64;
    if (which == 0)
      gemm_core(As, Bs, Pq, WqT, bq, nullptr, (void*)qaug,
                rowbase, colbase, BATCH * NTOK, DMODEL, 3);
    else
      gemm_core(As, Bs, Pk, WkT, bk, nullptr, (void*)kaug,
                rowbase, colbase, BATCH * NTOK, DMODEL, 4);
  } else {
    int sub = lid - 2376;
    int rowbase = (sub % 6) * 128;
    int colbase = (sub / 6) * 64;
    gemm_core(As, Bs, WvT, Pv, bv, (void*)vtg, nullptr,
              rowbase, colbase, DMODEL, BATCH * NTOK, 2);
  }
}

__global__ __launch_bounds__(256, 6) void gemm_proj_kernel(
    const short* __restrict__ Afin, const short* __restrict__ WpT,
    const float* __restrict__ bp, float* __restrict__ outp)
{
  __shared__ short As[2 * 4096];
  __shared__ short Bs[2 * 2048];
  const int NWG = 1188;
  int lid = xcd_chunk(blockIdx.x, NWG);
  int rowbase = (lid / 12) * 128;
  int colbase = (lid % 12) * 64;
  gemm_core(As, Bs, Afin, WpT, bp, (void*)outp, nullptr,
            rowbase, colbase, BATCH * NTOK, DMODEL, 0);
}

// -------------------------------------------------------- rel-pos bias tables
// MFMA version: one wave per (bh, line, mode) unit.
__global__ __launch_bounds__(256) void relbias2_kernel(
    const short* __restrict__ qaug_in, const float* __restrict__ rph,
    const float* __restrict__ rpw, short* __restrict__ qaug)
{
  int tid = threadIdx.x, wid = tid >> 6, lane = tid & 63;
  int l15 = lane & 15, lg = lane >> 4;
  int unit = blockIdx.x * 4 + wid;            // 0..10751
  int bh = unit / 56;
  int rem = unit - bh * 56;
  int line = rem >> 1;
  int mode = rem & 1;
  const float* rp = mode ? rpw : rph;
  const short* qb = qaug_in + (size_t)bh * NTOK * 128;

  bf16x8 aF[2][2];
#pragma unroll
  for (int tk = 0; tk < 2; ++tk) {
    int kk = tk * 16 + l15;
    int ridx = line - kk + 27;
    if (ridx < 0) ridx = 0;                  // kk>=28 lanes masked at store
    const float* rrow = rp + (size_t)ridx * HEAD_DIM;
#pragma unroll
    for (int c = 0; c < 2; ++c) {
      f32x4 f0 = *(const f32x4*)(rrow + c * 32 + lg * 8);
      f32x4 f1 = *(const f32x4*)(rrow + c * 32 + lg * 8 + 4);
      bf16x8 o;
#pragma unroll
      for (int e = 0; e < 4; ++e) { o[e] = f2bf(f0[e]); o[4 + e] = f2bf(f1[e]); }
      aF[tk][c] = o;
    }
  }
  bf16x8 bF[2][2];
#pragma unroll
  for (int tq = 0; tq < 2; ++tq) {
    int qr = tq * 16 + l15;
    int qrc = min(qr, PHDIM - 1);
    int qi = mode ? (1 + qrc * PHDIM + line) : (1 + line * PHDIM + qrc);
#pragma unroll
    for (int c = 0; c < 2; ++c)
      bF[tq][c] = *(const bf16x8*)(qb + (size_t)qi * 128 + c * 32 + lg * 8);
  }

  f32x4 s[2][2];
#pragma unroll
  for (int tq = 0; tq < 2; ++tq)
#pragma unroll
    for (int tk = 0; tk < 2; ++tk) {
      f32x4 a = (f32x4){0.f, 0.f, 0.f, 0.f};
      a = __builtin_amdgcn_mfma_f32_16x16x32_bf16(aF[tk][0], bF[tq][0], a, 0, 0, 0);
      a = __builtin_amdgcn_mfma_f32_16x16x32_bf16(aF[tk][1], bF[tq][1], a, 0, 0, 0);
      s[tq][tk] = a;
    }

  int dbase = mode ? 92 : 64;
#pragma unroll
  for (int tq = 0; tq < 2; ++tq) {
    int qr = tq * 16 + l15;
    if (qr >= PHDIM) continue;
    int qi = mode ? (1 + qr * PHDIM + line) : (1 + line * PHDIM + qr);
    short* dst = qaug + (size_t)bh * NTOK * 128 + (size_t)qi * 128 + dbase;
#pragma unroll
    for (int tk = 0; tk < 2; ++tk)
#pragma unroll
      for (int r = 0; r < 4; ++r) {
        int kk = tk * 16 + lg * 4 + r;
        if (kk < PHDIM) dst[kk] = f2bf(s[tq][tk][r] * 8.0f);
      }
  }
}

// ------------------------------------------------------------ flash attention
// flash7 (R15 proven): augmented QK; sigma-permuted K rows; lane-local P.
// S_exponent = s2 * mfma(K_aug, Q_aug), s2 = 0.125*log2e.
__global__ __launch_bounds__(256, 6) void flash7_kernel(
    const short* __restrict__ qaug, const short* __restrict__ kaug,
    const short* __restrict__ vtg, short* __restrict__ Afin)
{
  int id = blockIdx.x;
  int slot = id >> 3;
  int bh = (id & 7) * 24 + slot / 13;   // all 13 q-tiles of a bh on one XCD
  int qt = slot - (slot / 13) * 13;
  int qbase = qt * 64;
  int tid = threadIdx.x, wid = tid >> 6, lane = tid & 63;
  int lg = lane >> 4, lq = lane & 15;

  __shared__ __align__(16) short ks[64 * 128];   // sigma-permuted K_aug rows (16 slots, swz rr&15)
  __shared__ __align__(16) short vt[64 * 64];    // V^T[d][key] (8 slots, swz d&7)
  __shared__ __align__(16) float axl[4][16];

  int qi0 = qbase + wid * 16 + lq;
  int qiq = min(qi0, NTOK - 1);
  const short* qrow = qaug + ((size_t)bh * NTOK + qiq) * 128;
  bf16x8 bq[4];
#pragma unroll
  for (int c = 0; c < 4; ++c) bq[c] = *(const bf16x8*)(qrow + c * 32 + lg * 8);

  float m_l = -3e30f, l_l = 0.f;
  f32x4 acc[4];
#pragma unroll
  for (int ch = 0; ch < 4; ++ch) acc[ch] = (f32x4){0.f, 0.f, 0.f, 0.f};

  const float s2 = 0.125f * LOG2E;
  const short* kbase = kaug + (size_t)bh * NTOK * 128;
  const short* vbase = vtg + (size_t)bh * (size_t)HEAD_DIM * NTOK;

  int koffK[4], kslot[4];
#pragma unroll
  for (int m = 0; m < 4; ++m) {
    int c = m * 256 + tid;
    int rr = c >> 4, j = c & 15;
    koffK[m] = ((rr & 15) >> 2) * 16 + (rr >> 4) * 4 + (rr & 3);
    kslot[m] = (j ^ (rr & 15)) << 3;
  }
  int c0 = tid, c1 = 256 + tid;
  int vr0 = c0 >> 3, vj0 = c0 & 7;
  int vr1 = c1 >> 3, vj1 = c1 & 7;
  const short* vsrc0 = vbase + (size_t)vr0 * NTOK + ((vj0 ^ (vr0 & 7)) << 3);
  const short* vsrc1 = vbase + (size_t)vr1 * NTOK + ((vj1 ^ (vr1 & 7)) << 3);

  auto step_body = [&](int kvb, bool last) __attribute__((always_inline)) {
    __syncthreads();
#pragma unroll
    for (int m = 0; m < 4; ++m)
      gl_lds16(kbase + (size_t)min(kvb + koffK[m], NTOK - 1) * 128 + kslot[m],
               ks + m * 2048 + wid * 512);
    gl_lds16(vsrc0 + kvb, vt + wid * 512);
    gl_lds16(vsrc1 + kvb, vt + 2048 + wid * 512);
    __syncthreads();

    float p[16];
#pragma unroll
    for (int kt = 0; kt < 4; ++kt) {
      int kl = kt * 16 + lq;
      const char* kp = (const char*)ks + kl * 256;
      int swz = kl & 15;
      f32x4 s = (f32x4){0.f, 0.f, 0.f, 0.f};
      __builtin_amdgcn_s_setprio(1);
#pragma unroll
      for (int c = 0; c < 4; ++c) {
        bf16x8 aK = *(const bf16x8*)(kp + (((c * 4 + lg) ^ swz) << 4));
        s = __builtin_amdgcn_mfma_f32_16x16x32_bf16(aK, bq[c], s, 0, 0, 0);
      }
      __builtin_amdgcn_s_setprio(0);
#pragma unroll
      for (int r = 0; r < 4; ++r) {
        int i = kt * 4 + r;
        float v = s[r] * s2;
        if (last) {
          int key = kvb + 16 * lg + i;
          if (key >= NTOK) v = -3e30f;
        }
        p[i] = v;
      }
    }

    float pm = p[0];
#pragma unroll
    for (int i = 1; i < 16; ++i) pm = fmaxf(pm, p[i]);
    pm = fmaxf(pm, __shfl_xor(pm, 16));
    pm = fmaxf(pm, __shfl_xor(pm, 32));
    if (!__all(pm - m_l <= 11.5f)) {
      float mnew = fmaxf(m_l, pm);
      float alpha = fexp2(m_l - mnew);
      m_l = mnew;
      l_l *= alpha;
      if (lg == 0) axl[wid][lq] = alpha;
      f32x4 av = *(const f32x4*)&axl[wid][lg * 4];
#pragma unroll
      for (int ch = 0; ch < 4; ++ch)
#pragma unroll
        for (int r = 0; r < 4; ++r) acc[ch][r] *= av[r];
    }
    float ps = 0.f;
#pragma unroll
    for (int i = 0; i < 16; ++i) { p[i] = fexp2(p[i] - m_l); ps += p[i]; }
    ps += __shfl_xor(ps, 16);
    ps += __shfl_xor(ps, 32);
    l_l += ps;

    bf16x8 pa0, pa1;
#pragma unroll
    for (int j = 0; j < 4; ++j) {
      unsigned u0, u1, v0, v1;
      __builtin_memcpy(&u0, &p[2 * j], 4);
      __builtin_memcpy(&u1, &p[2 * j + 1], 4);
      __builtin_memcpy(&v0, &p[8 + 2 * j], 4);
      __builtin_memcpy(&v1, &p[8 + 2 * j + 1], 4);
      ((unsigned*)&pa0)[j] = (u0 >> 16) | (u1 & 0xFFFF0000u);
      ((unsigned*)&pa1)[j] = (v0 >> 16) | (v1 & 0xFFFF0000u);
    }
    __builtin_amdgcn_s_setprio(1);
#pragma unroll
    for (int ch = 0; ch < 4; ++ch) {
      int d = ch * 16 + lq;
      const char* vrow = (const char*)vt + d * 128;
      int swz = lq & 7;
      bf16x8 bv0 = *(const bf16x8*)(vrow + (((2 * lg + 0) ^ swz) << 4));
      bf16x8 bv1 = *(const bf16x8*)(vrow + (((2 * lg + 1) ^ swz) << 4));
      acc[ch] = __builtin_amdgcn_mfma_f32_16x16x32_bf16(pa0, bv0, acc[ch], 0, 0, 0);
      acc[ch] = __builtin_amdgcn_mfma_f32_16x16x32_bf16(pa1, bv1, acc[ch], 0, 0, 0);
    }
    __builtin_amdgcn_s_setprio(0);
  };

  for (int step = 0; step < 12; ++step) step_body(step * 64, false);
  step_body(12 * 64, true);

  if (lg == 0) axl[wid][lq] = l_l;
  f32x4 lv = *(const f32x4*)&axl[wid][lg * 4];
  int b = bh / NUM_HEADS, h = bh - b * NUM_HEADS;
#pragma unroll
  for (int r = 0; r < 4; ++r) {
    int qi = qbase + wid * 16 + lg * 4 + r;
    if (qi < NTOK) {
      float inv = 1.f / lv[r];
#pragma unroll
      for (int ch = 0; ch < 4; ++ch) {
        int d = ch * 16 + lq;
        float o = acc[ch][r] * inv + bf2f(qaug[((size_t)bh * NTOK + qi) * 128 + d]);
        Afin[((size_t)b * NTOK + qi) * DMODEL + h * HEAD_DIM + d] = f2bf(o);
      }
    }
  }
}

// ------------------------------------------------------------------- launcher
extern "C" void kernel_launch(void* const* d_in, const int* in_sizes, int n_in,
                              void* d_out, int out_size, void* d_ws, size_t ws_size,
                              hipStream_t stream)
{
  (void)in_sizes; (void)n_in; (void)out_size; (void)ws_size;
  const float* x   = (const float*)d_in[0];
  const float* pqw = (const float*)d_in[1];
  const float* pkw = (const float*)d_in[2];
  const float* pvw = (const float*)d_in[3];
  const float* gq  = (const float*)d_in[4];
  const float* bq_ = (const float*)d_in[5];
  const float* gk  = (const float*)d_in[6];
  const float* bk_ = (const float*)d_in[7];
  const float* gv  = (const float*)d_in[8];
  const float* bv_ = (const float*)d_in[9];
  const float* wq  = (const float*)d_in[10];
  const float* bqp = (const float*)d_in[11];
  const float* wk  = (const float*)d_in[12];
  const float* bkp = (const float*)d_in[13];
  const float* wv  = (const float*)d_in[14];
  const float* bvp = (const float*)d_in[15];
  const float* wp  = (const float*)d_in[16];
  const float* bpp = (const float*)d_in[17];
  const float* rph = (const float*)d_in[18];
  const float* rpw = (const float*)d_in[19];

  char* ws = (char*)d_ws;
  size_t off = 0;
  auto alloc = [&](size_t bytes) -> void* {
    void* p = ws + off; off += (bytes + 255) & ~(size_t)255; return p;
  };
  const size_t MROWS = (size_t)BATCH * NTOK;   // 12560
  short* Pq  = (short*)alloc(MROWS * DMODEL * 2);
  short* Pk  = (short*)alloc(MROWS * DMODEL * 2);
  short* Pv  = (short*)alloc(MROWS * DMODEL * 2);
  short* WqT = (short*)alloc((size_t)DMODEL * DMODEL * 2);
  short* WkT = (short*)alloc((size_t)DMODEL * DMODEL * 2);
  short* WvT = (short*)alloc((size_t)DMODEL * DMODEL * 2);
  short* WpT = (short*)alloc((size_t)DMODEL * DMODEL * 2);
  short* vtg = (short*)alloc(MROWS * DMODEL * 2 + 8192);   // transposed V
  short* qaug = (short*)alloc((size_t)BHCNT * NTOK * 128 * 2 + 8192);
  short* kaug = (short*)alloc((size_t)BHCNT * NTOK * 128 * 2 + 8192);
  short* Afin = (short*)alloc(MROWS * DMODEL * 2);

  pool_ln_kernel<<<dim3(16 * 197), 192, 0, stream>>>(
      x, pqw, pkw, pvw, gq, bq_, gk, bk_, gv, bv_, Pq, Pk, Pv);
  trans_kernel<<<dim3(24, 24, 4), dim3(32, 8), 0, stream>>>(
      wq, wk, wv, wp, WqT, WkT, WvT, WpT);
  gemm_qkv_kernel<<<dim3(3558), 256, 0, stream>>>(
      Pq, WqT, bqp, qaug, Pk, WkT, bkp, kaug, WvT, Pv, bvp, vtg);
  relbias2_kernel<<<dim3(2688), 256, 0, stream>>>(qaug, rph, rpw, qaug);
  flash7_kernel<<<dim3(2496), 256, 0, stream>>>(qaug, kaug, vtg, Afin);
  gemm_proj_kernel<<<dim3(1188), 256, 0, stream>>>(Afin, WpT, bpp, (float*)d_out);
}

// Round 22
// 307.883 us; speedup vs baseline: 1.0367x; 1.0367x over previous
//
#include <hip/hip_runtime.h>
#include <stdint.h>

#define NUM_HEADS 12
#define HEAD_DIM  64
#define HWDIM     56
#define PHDIM     28
#define NTOK      785     // 28*28+1
#define NIN       3137    // 56*56+1
#define BATCH     16
#define DMODEL    768
#define BHCNT     192     // BATCH*NUM_HEADS
#define LOG2E     1.44269504f

typedef __attribute__((ext_vector_type(8))) short bf16x8;
typedef __attribute__((ext_vector_type(4))) short s16x4;
typedef __attribute__((ext_vector_type(4))) float f32x4;

static __device__ __forceinline__ float bf2f(short s) {
  unsigned u = ((unsigned)(unsigned short)s) << 16;
  float f; __builtin_memcpy(&f, &u, 4); return f;
}
static __device__ __forceinline__ short f2bf(float f) {
  unsigned u; __builtin_memcpy(&u, &f, 4);
  unsigned r = u + 0x7FFFu + ((u >> 16) & 1u);
  return (short)(r >> 16);
}
static __device__ __forceinline__ float fexp2(float x) {
#if defined(__has_builtin)
#if __has_builtin(__builtin_amdgcn_exp2f)
  return __builtin_amdgcn_exp2f(x);
#else
  return exp2f(x);
#endif
#else
  return exp2f(x);
#endif
}

// bijective XCD chunking (m204)
static __device__ __forceinline__ int xcd_chunk(int orig, int nwg) {
  int xcd = orig & 7;
  int within = orig >> 3;
  int q = nwg >> 3, r = nwg & 7;
  int base = (xcd < r) ? xcd * (q + 1) : r * (q + 1) + (xcd - r) * q;
  return base + within;
}

#if defined(__has_builtin)
#if __has_builtin(__builtin_amdgcn_global_load_lds)
#define HAVE_GLLDS 1
#endif
#endif

static __device__ __forceinline__ void gl_lds16(const short* g, short* l) {
#ifdef HAVE_GLLDS
  __builtin_amdgcn_global_load_lds(
      (const __attribute__((address_space(1))) void*)g,
      (__attribute__((address_space(3))) void*)l, 16, 0, 0);
#else
  int lane = threadIdx.x & 63;
  *(bf16x8*)(l + lane * 8) = *(const bf16x8*)g;
#endif
}

// ---------------------------------------------------------------- pool + LN
__global__ __launch_bounds__(192) void pool_ln_kernel(
    const float* __restrict__ x,
    const float* __restrict__ wq9, const float* __restrict__ wk9, const float* __restrict__ wv9,
    const float* __restrict__ gq, const float* __restrict__ bq,
    const float* __restrict__ gk, const float* __restrict__ bk,
    const float* __restrict__ gv, const float* __restrict__ bv,
    short* __restrict__ Pq, short* __restrict__ Pk, short* __restrict__ Pv)
{
  __shared__ __align__(16) float wt_s[3][9][64];   // [conv][tap][c]
  int tid = threadIdx.x;
  int blk = xcd_chunk(blockIdx.x, 16 * 197);   // L2 locality: neighbors same XCD
  int b = blk / 197;
  int n0 = (blk - b * 197) * 4;

  for (int idx = tid; idx < 3 * 576; idx += 192) {
    int conv = idx / 576, rem = idx - conv * 576;
    int c = rem / 9, tap = rem - c * 9;
    const float* wsrc = (conv == 0) ? wq9 : (conv == 1) ? wk9 : wv9;
    wt_s[conv][tap][c] = wsrc[c * 9 + tap];
  }
  __syncthreads();

  int ch0 = tid * 4;
  int c4 = ch0 & 63;
  f32x4 g_q = *(const f32x4*)&gq[c4], b_q = *(const f32x4*)&bq[c4];
  f32x4 g_k = *(const f32x4*)&gk[c4], b_k = *(const f32x4*)&bk[c4];
  f32x4 g_v = *(const f32x4*)&gv[c4], b_v = *(const f32x4*)&bv[c4];

  for (int tt = 0; tt < 4; ++tt) {
    int n = n0 + tt;
    if (n >= NTOK) break;
    f32x4 aq = (f32x4){0.f, 0.f, 0.f, 0.f}, ak = aq, av = aq;
    if (n == 0) {
      f32x4 x4 = *(const f32x4*)&x[((size_t)b * NIN) * DMODEL + ch0];
      aq = ak = av = x4;
    } else {
      int s = n - 1;
      int i = s / PHDIM, j = s - i * PHDIM;
#pragma unroll
      for (int di = 0; di < 3; ++di) {
        int ii = 2 * i - 1 + di;
        if (ii < 0 || ii >= HWDIM) continue;
#pragma unroll
        for (int dj = 0; dj < 3; ++dj) {
          int jj = 2 * j - 1 + dj;
          if (jj < 0 || jj >= HWDIM) continue;
          f32x4 x4 = *(const f32x4*)&x[((size_t)b * NIN + 1 + ii * HWDIM + jj) * DMODEL + ch0];
          int tap = di * 3 + dj;
          f32x4 w0 = *(const f32x4*)&wt_s[0][tap][c4];
          f32x4 w1 = *(const f32x4*)&wt_s[1][tap][c4];
          f32x4 w2 = *(const f32x4*)&wt_s[2][tap][c4];
          aq += w0 * x4; ak += w1 * x4; av += w2 * x4;
        }
      }
    }
    size_t obase = ((size_t)b * NTOK + n) * DMODEL + ch0;
    {
      float sm = aq[0] + aq[1] + aq[2] + aq[3];
#pragma unroll
      for (int m = 1; m < 16; m <<= 1) sm += __shfl_xor(sm, m);
      float mn = sm * (1.f / 64.f);
      f32x4 d = aq - mn;
      float vs = d[0]*d[0] + d[1]*d[1] + d[2]*d[2] + d[3]*d[3];
#pragma unroll
      for (int m = 1; m < 16; m <<= 1) vs += __shfl_xor(vs, m);
      float rs = rsqrtf(vs * (1.f / 64.f) + 1e-5f);
      s16x4 o;
#pragma unroll
      for (int e = 0; e < 4; ++e) o[e] = f2bf(d[e] * rs * g_q[e] + b_q[e]);
      *(s16x4*)&Pq[obase] = o;
    }
    {
      float sm = ak[0] + ak[1] + ak[2] + ak[3];
#pragma unroll
      for (int m = 1; m < 16; m <<= 1) sm += __shfl_xor(sm, m);
      float mn = sm * (1.f / 64.f);
      f32x4 d = ak - mn;
      float vs = d[0]*d[0] + d[1]*d[1] + d[2]*d[2] + d[3]*d[3];
#pragma unroll
      for (int m = 1; m < 16; m <<= 1) vs += __shfl_xor(vs, m);
      float rs = rsqrtf(vs * (1.f / 64.f) + 1e-5f);
      s16x4 o;
#pragma unroll
      for (int e = 0; e < 4; ++e) o[e] = f2bf(d[e] * rs * g_k[e] + b_k[e]);
      *(s16x4*)&Pk[obase] = o;
    }
    {
      float sm = av[0] + av[1] + av[2] + av[3];
#pragma unroll
      for (int m = 1; m < 16; m <<= 1) sm += __shfl_xor(sm, m);
      float mn = sm * (1.f / 64.f);
      f32x4 d = av - mn;
      float vs = d[0]*d[0] + d[1]*d[1] + d[2]*d[2] + d[3]*d[3];
#pragma unroll
      for (int m = 1; m < 16; m <<= 1) vs += __shfl_xor(vs, m);
      float rs = rsqrtf(vs * (1.f / 64.f) + 1e-5f);
      s16x4 o;
#pragma unroll
      for (int e = 0; e < 4; ++e) o[e] = f2bf(d[e] * rs * g_v[e] + b_v[e]);
      *(s16x4*)&Pv[obase] = o;
    }
  }
}

// ------------------------------------------------- weight transpose fp32->bf16
__global__ __launch_bounds__(256) void trans_kernel(
    const float* __restrict__ s0, const float* __restrict__ s1,
    const float* __restrict__ s2, const float* __restrict__ s3,
    short* __restrict__ d0, short* __restrict__ d1,
    short* __restrict__ d2, short* __restrict__ d3)
{
  __shared__ float tile[32][33];
  int z = blockIdx.z;
  const float* s = (z == 0) ? s0 : (z == 1) ? s1 : (z == 2) ? s2 : s3;
  short* d = (z == 0) ? d0 : (z == 1) ? d1 : (z == 2) ? d2 : d3;
  int k0 = blockIdx.x * 32, n0 = blockIdx.y * 32;
  int tx = threadIdx.x, ty = threadIdx.y;   // 32 x 8
#pragma unroll
  for (int jj = 0; jj < 4; ++jj)
    tile[ty + jj * 8][tx] = s[(size_t)(k0 + ty + jj * 8) * DMODEL + n0 + tx];
  __syncthreads();
#pragma unroll
  for (int jj = 0; jj < 4; ++jj)
    d[(size_t)(n0 + ty + jj * 8) * DMODEL + k0 + tx] = f2bf(tile[tx][ty + jj * 8]);
}

// ------------------------------------------------------------- GEMM core (R15)
// 128x64 tile, BK=32, 2-phase dbuf, 4 waves each owning 64x32.
static __device__ __forceinline__ void gemm_core(
    short* As, short* Bs,
    const short* __restrict__ A, const short* __restrict__ Bt,
    const float* __restrict__ bias, void* __restrict__ outp, void* __restrict__ outp2,
    int rowbase, int colbase, int M, int Nn, int mode)
{
  const int K = DMODEL;
  int tid = threadIdx.x;
  int wid = tid >> 6, lane = tid & 63;
  int lg = lane >> 4, lq = lane & 15;
  int wm = wid >> 1, wn = wid & 1;

  f32x4 acc[4][2];
#pragma unroll
  for (int i = 0; i < 4; ++i)
#pragma unroll
    for (int j = 0; j < 2; ++j) acc[i][j] = (f32x4){0.f, 0.f, 0.f, 0.f};

  const short* AgP[2];
  const short* BgP;
  {
#pragma unroll
    for (int m = 0; m < 2; ++m) {
      int ch = m * 256 + tid;
      int row = ch >> 2, j = ch & 3;
      int gcol = (j ^ (row & 3)) << 3;
      int ar = min(rowbase + row, M - 1);
      AgP[m] = A + (size_t)ar * K + gcol;
    }
    int ch = tid;
    int row = ch >> 2, j = ch & 3;
    int gcol = (j ^ (row & 3)) << 3;
    int br = min(colbase + row, Nn - 1);
    BgP = Bt + (size_t)br * K + gcol;
  }

  auto stage = [&](int kt, int buf) __attribute__((always_inline)) {
    short* Ab = As + buf * 4096;
    short* Bb = Bs + buf * 2048;
#pragma unroll
    for (int m = 0; m < 2; ++m)
      gl_lds16(AgP[m] + kt, Ab + m * 2048 + wid * 512);
    gl_lds16(BgP + kt, Bb + wid * 512);
  };

  stage(0, 0);
  __syncthreads();
  int cur = 0;
  for (int kt = 0; kt < K; kt += 32) {
    if (kt + 32 < K) stage(kt + 32, cur ^ 1);
    const short* Ac = As + cur * 4096;
    const short* Bc = Bs + cur * 2048;
    bf16x8 aFrag[4], bFrag[2];
#pragma unroll
    for (int mi = 0; mi < 4; ++mi) {
      int r = wm * 64 + mi * 16 + lq;
      int slot = lg ^ (r & 3);
      aFrag[mi] = *(const bf16x8*)&Ac[r * 32 + slot * 8];
    }
#pragma unroll
    for (int ni = 0; ni < 2; ++ni) {
      int r = wn * 32 + ni * 16 + lq;
      int slot = lg ^ (r & 3);
      bFrag[ni] = *(const bf16x8*)&Bc[r * 32 + slot * 8];
    }
    __builtin_amdgcn_s_setprio(1);
#pragma unroll
    for (int mi = 0; mi < 4; ++mi)
#pragma unroll
      for (int ni = 0; ni < 2; ++ni)
        acc[mi][ni] = __builtin_amdgcn_mfma_f32_16x16x32_bf16(aFrag[mi], bFrag[ni], acc[mi][ni], 0, 0, 0);
    __builtin_amdgcn_s_setprio(0);
    __syncthreads();
    cur ^= 1;
  }

  if (mode >= 3) {
    int myhead = colbase >> 6;
#pragma unroll
    for (int mi = 0; mi < 4; ++mi) {
      int rowq = rowbase + wm * 64 + mi * 16 + lg * 4;
#pragma unroll
      for (int r = 0; r < 4; ++r) {
        int row = rowq + r;
        if (row < M) {
          int bb = row / NTOK, nn = row - bb * NTOK;
          size_t abase = ((size_t)(bb * NUM_HEADS + myhead) * NTOK + nn) * 128;
#pragma unroll
          for (int ni = 0; ni < 2; ++ni) {
            int col = colbase + wn * 32 + ni * 16 + lq;
            int c = col & 63;
            float v = acc[mi][ni][r] + bias[col];
            ((short*)outp2)[abase + c] = f2bf(v);
          }
        }
      }
    }
    // aug upper half: every block writes its own head (no stale-memory deps)
    {
      int rz = rowbase + wn * 64 + wm * 32 + (lane >> 1);   // 1 writer per row
      if ((lane & 1) == 0 && rz < M) {
        int bb = rz / NTOK, nn = rz - bb * NTOK;
        short* dst = (short*)outp2 + ((size_t)(bb * NUM_HEADS + myhead) * NTOK + nn) * 128 + 64;
        bf16x8 z = {0, 0, 0, 0, 0, 0, 0, 0};
        if (mode == 3) {
          // relbias overwrites dims [64:120) for nn>=1; we own [120:128)
          *(bf16x8*)(dst + 56) = z;
          if (nn == 0) {
#pragma unroll
            for (int zc = 0; zc < 7; ++zc) *(bf16x8*)(dst + zc * 8) = z;
          }
        } else {
          int ki = -100, kj = -100;
          if (nn >= 1) { int km1 = nn - 1; ki = km1 / PHDIM; kj = km1 - ki * PHDIM; }
#pragma unroll
          for (int zc = 0; zc < 8; ++zc) {
            bf16x8 o = {0, 0, 0, 0, 0, 0, 0, 0};
#pragma unroll
            for (int e = 0; e < 8; ++e) {
              int d = 64 + zc * 8 + e;
              if (d == 64 + ki || d == 92 + kj) o[e] = (short)0x3F80;
            }
            *(bf16x8*)(dst + zc * 8) = o;
          }
        }
      }
    }
    return;
  }

#pragma unroll
  for (int mi = 0; mi < 4; ++mi) {
    int rowq = rowbase + wm * 64 + mi * 16 + lg * 4;
#pragma unroll
    for (int r = 0; r < 4; ++r) {
      int row = rowq + r;
      if (row < M) {
        if (mode == 2) {
          float bb = bias[row];
#pragma unroll
          for (int ni = 0; ni < 2; ++ni) {
            int col = colbase + wn * 32 + ni * 16 + lq;
            if (col < Nn) {
              int b = col / NTOK, n = col - b * NTOK;
              float v = acc[mi][ni][r] + bb;
              ((short*)outp)[((size_t)b * DMODEL + row) * NTOK + n] = f2bf(v);
            }
          }
        } else {
#pragma unroll
          for (int ni = 0; ni < 2; ++ni) {
            int col = colbase + wn * 32 + ni * 16 + lq;
            float v = acc[mi][ni][r] + bias[col];
            ((float*)outp)[(size_t)row * DMODEL + col] = v;
          }
        }
      }
    }
  }
}

__global__ __launch_bounds__(256, 6) void gemm_qkv_kernel(
    const short* __restrict__ Pq, const short* __restrict__ WqT,
    const float* __restrict__ bq, short* __restrict__ qaug,
    const short* __restrict__ Pk, const short* __restrict__ WkT,
    const float* __restrict__ bk, short* __restrict__ kaug,
    const short* __restrict__ WvT, const short* __restrict__ Pv,
    const float* __restrict__ bv, short* __restrict__ vtg)
{
  __shared__ short As[2 * 4096];
  __shared__ short Bs[2 * 2048];
  const int NWG = 3558;
  int lid = xcd_chunk(blockIdx.x, NWG);
  if (lid < 2376) {
    int which = lid / 1188;
    int sub = lid - which * 1188;
    int rowbase = (sub / 12) * 128;
    int colbase = (sub % 12) * 64;
    if (which == 0)
      gemm_core(As, Bs, Pq, WqT, bq, nullptr, (void*)qaug,
                rowbase, colbase, BATCH * NTOK, DMODEL, 3);
    else
      gemm_core(As, Bs, Pk, WkT, bk, nullptr, (void*)kaug,
                rowbase, colbase, BATCH * NTOK, DMODEL, 4);
  } else {
    int sub = lid - 2376;
    int rowbase = (sub % 6) * 128;
    int colbase = (sub / 6) * 64;
    gemm_core(As, Bs, WvT, Pv, bv, (void*)vtg, nullptr,
              rowbase, colbase, DMODEL, BATCH * NTOK, 2);
  }
}

__global__ __launch_bounds__(256, 6) void gemm_proj_kernel(
    const short* __restrict__ Afin, const short* __restrict__ WpT,
    const float* __restrict__ bp, float* __restrict__ outp)
{
  __shared__ short As[2 * 4096];
  __shared__ short Bs[2 * 2048];
  const int NWG = 1188;
  int lid = xcd_chunk(blockIdx.x, NWG);
  int rowbase = (lid / 12) * 128;
  int colbase = (lid % 12) * 64;
  gemm_core(As, Bs, Afin, WpT, bp, (void*)outp, nullptr,
            rowbase, colbase, BATCH * NTOK, DMODEL, 0);
}

// -------------------------------------------------------- rel-pos bias tables
// MFMA version: one wave per (bh, line, mode) unit.
__global__ __launch_bounds__(256) void relbias2_kernel(
    const short* __restrict__ qaug_in, const float* __restrict__ rph,
    const float* __restrict__ rpw, short* __restrict__ qaug)
{
  int tid = threadIdx.x, wid = tid >> 6, lane = tid & 63;
  int l15 = lane & 15, lg = lane >> 4;
  int unit = blockIdx.x * 4 + wid;            // 0..10751
  int bh = unit / 56;
  int rem = unit - bh * 56;
  int line = rem >> 1;
  int mode = rem & 1;
  const float* rp = mode ? rpw : rph;
  const short* qb = qaug_in + (size_t)bh * NTOK * 128;

  bf16x8 aF[2][2];
#pragma unroll
  for (int tk = 0; tk < 2; ++tk) {
    int kk = tk * 16 + l15;
    int ridx = line - kk + 27;
    if (ridx < 0) ridx = 0;                  // kk>=28 lanes masked at store
    const float* rrow = rp + (size_t)ridx * HEAD_DIM;
#pragma unroll
    for (int c = 0; c < 2; ++c) {
      f32x4 f0 = *(const f32x4*)(rrow + c * 32 + lg * 8);
      f32x4 f1 = *(const f32x4*)(rrow + c * 32 + lg * 8 + 4);
      bf16x8 o;
#pragma unroll
      for (int e = 0; e < 4; ++e) { o[e] = f2bf(f0[e]); o[4 + e] = f2bf(f1[e]); }
      aF[tk][c] = o;
    }
  }
  bf16x8 bF[2][2];
#pragma unroll
  for (int tq = 0; tq < 2; ++tq) {
    int qr = tq * 16 + l15;
    int qrc = min(qr, PHDIM - 1);
    int qi = mode ? (1 + qrc * PHDIM + line) : (1 + line * PHDIM + qrc);
#pragma unroll
    for (int c = 0; c < 2; ++c)
      bF[tq][c] = *(const bf16x8*)(qb + (size_t)qi * 128 + c * 32 + lg * 8);
  }

  f32x4 s[2][2];
#pragma unroll
  for (int tq = 0; tq < 2; ++tq)
#pragma unroll
    for (int tk = 0; tk < 2; ++tk) {
      f32x4 a = (f32x4){0.f, 0.f, 0.f, 0.f};
      a = __builtin_amdgcn_mfma_f32_16x16x32_bf16(aF[tk][0], bF[tq][0], a, 0, 0, 0);
      a = __builtin_amdgcn_mfma_f32_16x16x32_bf16(aF[tk][1], bF[tq][1], a, 0, 0, 0);
      s[tq][tk] = a;
    }

  int dbase = mode ? 92 : 64;
#pragma unroll
  for (int tq = 0; tq < 2; ++tq) {
    int qr = tq * 16 + l15;
    if (qr >= PHDIM) continue;
    int qi = mode ? (1 + qr * PHDIM + line) : (1 + line * PHDIM + qr);
    short* dst = qaug + (size_t)bh * NTOK * 128 + (size_t)qi * 128 + dbase;
#pragma unroll
    for (int tk = 0; tk < 2; ++tk)
#pragma unroll
      for (int r = 0; r < 4; ++r) {
        int kk = tk * 16 + lg * 4 + r;
        if (kk < PHDIM) dst[kk] = f2bf(s[tq][tk][r] * 8.0f);
      }
  }
}

// ------------------------------------------------------------ flash attention
// flash7 (R15 proven): augmented QK; sigma-permuted K rows; lane-local P.
// S_exponent = s2 * mfma(K_aug, Q_aug), s2 = 0.125*log2e.
__global__ __launch_bounds__(256) void flash7_kernel(
    const short* __restrict__ qaug, const short* __restrict__ kaug,
    const short* __restrict__ vtg, short* __restrict__ Afin)
{
  int id = blockIdx.x;
  int slot = id >> 3;
  int bh = (id & 7) * 24 + slot / 13;   // all 13 q-tiles of a bh on one XCD
  int qt = slot - (slot / 13) * 13;
  int qbase = qt * 64;
  int tid = threadIdx.x, wid = tid >> 6, lane = tid & 63;
  int lg = lane >> 4, lq = lane & 15;

  __shared__ __align__(16) short ks[64 * 128];   // sigma-permuted K_aug rows (16 slots, swz rr&15)
  __shared__ __align__(16) short vt[64 * 64];    // V^T[d][key] (8 slots, swz d&7)
  __shared__ __align__(16) float axl[4][16];

  int qi0 = qbase + wid * 16 + lq;
  int qiq = min(qi0, NTOK - 1);
  const short* qrow = qaug + ((size_t)bh * NTOK + qiq) * 128;
  bf16x8 bq[4];
#pragma unroll
  for (int c = 0; c < 4; ++c) bq[c] = *(const bf16x8*)(qrow + c * 32 + lg * 8);

  float m_l = -3e30f, l_l = 0.f;
  f32x4 acc[4];
#pragma unroll
  for (int ch = 0; ch < 4; ++ch) acc[ch] = (f32x4){0.f, 0.f, 0.f, 0.f};

  const float s2 = 0.125f * LOG2E;
  const short* kbase = kaug + (size_t)bh * NTOK * 128;
  const short* vbase = vtg + (size_t)bh * (size_t)HEAD_DIM * NTOK;

  int koffK[4], kslot[4];
#pragma unroll
  for (int m = 0; m < 4; ++m) {
    int c = m * 256 + tid;
    int rr = c >> 4, j = c & 15;
    koffK[m] = ((rr & 15) >> 2) * 16 + (rr >> 4) * 4 + (rr & 3);
    kslot[m] = (j ^ (rr & 15)) << 3;
  }
  int c0 = tid, c1 = 256 + tid;
  int vr0 = c0 >> 3, vj0 = c0 & 7;
  int vr1 = c1 >> 3, vj1 = c1 & 7;
  const short* vsrc0 = vbase + (size_t)vr0 * NTOK + ((vj0 ^ (vr0 & 7)) << 3);
  const short* vsrc1 = vbase + (size_t)vr1 * NTOK + ((vj1 ^ (vr1 & 7)) << 3);

  auto step_body = [&](int kvb, bool last) __attribute__((always_inline)) {
    __syncthreads();
#pragma unroll
    for (int m = 0; m < 4; ++m)
      gl_lds16(kbase + (size_t)min(kvb + koffK[m], NTOK - 1) * 128 + kslot[m],
               ks + m * 2048 + wid * 512);
    gl_lds16(vsrc0 + kvb, vt + wid * 512);
    gl_lds16(vsrc1 + kvb, vt + 2048 + wid * 512);
    __syncthreads();

    float p[16];
#pragma unroll
    for (int kt = 0; kt < 4; ++kt) {
      int kl = kt * 16 + lq;
      const char* kp = (const char*)ks + kl * 256;
      int swz = kl & 15;
      f32x4 s = (f32x4){0.f, 0.f, 0.f, 0.f};
      __builtin_amdgcn_s_setprio(1);
#pragma unroll
      for (int c = 0; c < 4; ++c) {
        bf16x8 aK = *(const bf16x8*)(kp + (((c * 4 + lg) ^ swz) << 4));
        s = __builtin_amdgcn_mfma_f32_16x16x32_bf16(aK, bq[c], s, 0, 0, 0);
      }
      __builtin_amdgcn_s_setprio(0);
#pragma unroll
      for (int r = 0; r < 4; ++r) {
        int i = kt * 4 + r;
        float v = s[r] * s2;
        if (last) {
          int key = kvb + 16 * lg + i;
          if (key >= NTOK) v = -3e30f;
        }
        p[i] = v;
      }
    }

    float pm = p[0];
#pragma unroll
    for (int i = 1; i < 16; ++i) pm = fmaxf(pm, p[i]);
    pm = fmaxf(pm, __shfl_xor(pm, 16));
    pm = fmaxf(pm, __shfl_xor(pm, 32));
    if (!__all(pm - m_l <= 11.5f)) {
      float mnew = fmaxf(m_l, pm);
      float alpha = fexp2(m_l - mnew);
      m_l = mnew;
      l_l *= alpha;
      if (lg == 0) axl[wid][lq] = alpha;
      f32x4 av = *(const f32x4*)&axl[wid][lg * 4];
#pragma unroll
      for (int ch = 0; ch < 4; ++ch)
#pragma unroll
        for (int r = 0; r < 4; ++r) acc[ch][r] *= av[r];
    }
    float ps = 0.f;
#pragma unroll
    for (int i = 0; i < 16; ++i) { p[i] = fexp2(p[i] - m_l); ps += p[i]; }
    ps += __shfl_xor(ps, 16);
    ps += __shfl_xor(ps, 32);
    l_l += ps;

    bf16x8 pa0, pa1;
#pragma unroll
    for (int j = 0; j < 4; ++j) {
      unsigned u0, u1, v0, v1;
      __builtin_memcpy(&u0, &p[2 * j], 4);
      __builtin_memcpy(&u1, &p[2 * j + 1], 4);
      __builtin_memcpy(&v0, &p[8 + 2 * j], 4);
      __builtin_memcpy(&v1, &p[8 + 2 * j + 1], 4);
      ((unsigned*)&pa0)[j] = (u0 >> 16) | (u1 & 0xFFFF0000u);
      ((unsigned*)&pa1)[j] = (v0 >> 16) | (v1 & 0xFFFF0000u);
    }
    __builtin_amdgcn_s_setprio(1);
#pragma unroll
    for (int ch = 0; ch < 4; ++ch) {
      int d = ch * 16 + lq;
      const char* vrow = (const char*)vt + d * 128;
      int swz = lq & 7;
      bf16x8 bv0 = *(const bf16x8*)(vrow + (((2 * lg + 0) ^ swz) << 4));
      bf16x8 bv1 = *(const bf16x8*)(vrow + (((2 * lg + 1) ^ swz) << 4));
      acc[ch] = __builtin_amdgcn_mfma_f32_16x16x32_bf16(pa0, bv0, acc[ch], 0, 0, 0);
      acc[ch] = __builtin_amdgcn_mfma_f32_16x16x32_bf16(pa1, bv1, acc[ch], 0, 0, 0);
    }
    __builtin_amdgcn_s_setprio(0);
  };

  for (int step = 0; step < 12; ++step) step_body(step * 64, false);
  step_body(12 * 64, true);

  if (lg == 0) axl[wid][lq] = l_l;
  f32x4 lv = *(const f32x4*)&axl[wid][lg * 4];
  int b = bh / NUM_HEADS, h = bh - b * NUM_HEADS;
#pragma unroll
  for (int r = 0; r < 4; ++r) {
    int qi = qbase + wid * 16 + lg * 4 + r;
    if (qi < NTOK) {
      float inv = 1.f / lv[r];
#pragma unroll
      for (int ch = 0; ch < 4; ++ch) {
        int d = ch * 16 + lq;
        float o = acc[ch][r] * inv + bf2f(qaug[((size_t)bh * NTOK + qi) * 128 + d]);
        Afin[((size_t)b * NTOK + qi) * DMODEL + h * HEAD_DIM + d] = f2bf(o);
      }
    }
  }
}

// ------------------------------------------------------------------- launcher
extern "C" void kernel_launch(void* const* d_in, const int* in_sizes, int n_in,
                              void* d_out, int out_size, void* d_ws, size_t ws_size,
                              hipStream_t stream)
{
  (void)in_sizes; (void)n_in; (void)out_size; (void)ws_size;
  const float* x   = (const float*)d_in[0];
  const float* pqw = (const float*)d_in[1];
  const float* pkw = (const float*)d_in[2];
  const float* pvw = (const float*)d_in[3];
  const float* gq  = (const float*)d_in[4];
  const float* bq_ = (const float*)d_in[5];
  const float* gk  = (const float*)d_in[6];
  const float* bk_ = (const float*)d_in[7];
  const float* gv  = (const float*)d_in[8];
  const float* bv_ = (const float*)d_in[9];
  const float* wq  = (const float*)d_in[10];
  const float* bqp = (const float*)d_in[11];
  const float* wk  = (const float*)d_in[12];
  const float* bkp = (const float*)d_in[13];
  const float* wv  = (const float*)d_in[14];
  const float* bvp = (const float*)d_in[15];
  const float* wp  = (const float*)d_in[16];
  const float* bpp = (const float*)d_in[17];
  const float* rph = (const float*)d_in[18];
  const float* rpw = (const float*)d_in[19];

  char* ws = (char*)d_ws;
  size_t off = 0;
  auto alloc = [&](size_t bytes) -> void* {
    void* p = ws + off; off += (bytes + 255) & ~(size_t)255; return p;
  };
  const size_t MROWS = (size_t)BATCH * NTOK;   // 12560
  short* Pq  = (short*)alloc(MROWS * DMODEL * 2);
  short* Pk  = (short*)alloc(MROWS * DMODEL * 2);
  short* Pv  = (short*)alloc(MROWS * DMODEL * 2);
  short* WqT = (short*)alloc((size_t)DMODEL * DMODEL * 2);
  short* WkT = (short*)alloc((size_t)DMODEL * DMODEL * 2);
  short* WvT = (short*)alloc((size_t)DMODEL * DMODEL * 2);
  short* WpT = (short*)alloc((size_t)DMODEL * DMODEL * 2);
  short* vtg = (short*)alloc(MROWS * DMODEL * 2 + 8192);   // transposed V
  short* qaug = (short*)alloc((size_t)BHCNT * NTOK * 128 * 2 + 8192);
  short* kaug = (short*)alloc((size_t)BHCNT * NTOK * 128 * 2 + 8192);
  short* Afin = (short*)alloc(MROWS * DMODEL * 2);

  pool_ln_kernel<<<dim3(16 * 197), 192, 0, stream>>>(
      x, pqw, pkw, pvw, gq, bq_, gk, bk_, gv, bv_, Pq, Pk, Pv);
  trans_kernel<<<dim3(24, 24, 4), dim3(32, 8), 0, stream>>>(
      wq, wk, wv, wp, WqT, WkT, WvT, WpT);
  gemm_qkv_kernel<<<dim3(3558), 256, 0, stream>>>(
      Pq, WqT, bqp, qaug, Pk, WkT, bkp, kaug, WvT, Pv, bvp, vtg);
  relbias2_kernel<<<dim3(2688), 256, 0, stream>>>(qaug, rph, rpw, qaug);
  flash7_kernel<<<dim3(2496), 256, 0, stream>>>(qaug, kaug, vtg, Afin);
  gemm_proj_kernel<<<dim3(1188), 256, 0, stream>>>(Afin, WpT, bpp, (float*)d_out);
}